// Round 1
// baseline (144.281 us; speedup 1.0000x reference)
//
#include <hip/hip_runtime.h>

// BeliefUpdate: belief_{t+1} = softmax(log(belief_t + eps) + log_lik)
//             = (belief_t + eps) * W / sum((belief_t + eps) * W),
//   W = (lik+eps)*(m0+eps)*(m1+eps)   (exact softmax identity, no exp/log needed)
// Global (scalar) convergence flag => all rows freeze at the same iteration.
// Phase A: per-row 10-iteration trajectory fully in registers, record per-iter
//          global max-change via block-reduce + spread atomicMax; write b_10.
// Finalize: find first iter with change < 1e-4 -> iters; write iters (as float)
//           and a recompute flag.
// Phase C: only if iters < 10 (a.s. never for random uniforms): recompute b_iters.

static constexpr int   kD      = 256;
static constexpr float kEps    = 1e-10f;
static constexpr float kThresh = 1e-4f;
static constexpr int   kIters  = 10;
static constexpr int   kSlots  = 64;   // spread atomic slots per iteration index

__global__ __launch_bounds__(256) void bu_init(unsigned* __restrict__ slots) {
    for (int i = threadIdx.x; i < kIters * kSlots; i += 256) slots[i] = 0u;
}

// 256 threads = 4 waves; each wave handles 4 rows (16-lane groups, 16 elems/lane)
__global__ __launch_bounds__(256) void bu_phaseA(
    const float* __restrict__ prior,
    const float* __restrict__ lik,
    const float* __restrict__ msg,
    float* __restrict__ belief,
    unsigned* __restrict__ slots,
    int B)
{
    const int wave = threadIdx.x >> 6;
    const int lane = threadIdx.x & 63;
    const int g    = lane >> 4;       // row within the wave's quad
    const int q    = lane & 15;       // position within 16-lane group
    const int row  = (blockIdx.x * 4 + wave) * 4 + g;
    const size_t off = (size_t)row * kD + (size_t)q * 16;

    const float* p0 = prior + off;
    const float* p1 = lik   + off;
    const float* p2 = msg   + off;                      // messages[0]
    const float* p3 = msg   + (size_t)B * kD + off;     // messages[1]

    float b[16], W[16];
    #pragma unroll
    for (int c = 0; c < 4; ++c) {
        float4 vb = *(const float4*)(p0 + 4 * c);
        float4 vl = *(const float4*)(p1 + 4 * c);
        float4 v0 = *(const float4*)(p2 + 4 * c);
        float4 v1 = *(const float4*)(p3 + 4 * c);
        b[4*c+0] = vb.x; b[4*c+1] = vb.y; b[4*c+2] = vb.z; b[4*c+3] = vb.w;
        W[4*c+0] = (vl.x + kEps) * (v0.x + kEps) * (v1.x + kEps);
        W[4*c+1] = (vl.y + kEps) * (v0.y + kEps) * (v1.y + kEps);
        W[4*c+2] = (vl.z + kEps) * (v0.z + kEps) * (v1.z + kEps);
        W[4*c+3] = (vl.w + kEps) * (v0.w + kEps) * (v1.w + kEps);
    }

    float chg[kIters];
    #pragma unroll
    for (int t = 0; t < kIters; ++t) {
        float pp[16];
        float s = 0.f;
        #pragma unroll
        for (int j = 0; j < 16; ++j) { pp[j] = (b[j] + kEps) * W[j]; s += pp[j]; }
        // 16-lane group sum (xor 1,2,4,8 stays inside the group)
        s += __shfl_xor(s, 1);
        s += __shfl_xor(s, 2);
        s += __shfl_xor(s, 4);
        s += __shfl_xor(s, 8);
        const float inv = 1.0f / s;
        float c = 0.f;
        #pragma unroll
        for (int j = 0; j < 16; ++j) {
            float nb  = pp[j] * inv;
            float upd = b[j] + (nb - b[j]);   // mimic reference: b + LR*(nb-b), LR=1
            c = fmaxf(c, fabsf(upd - b[j]));
            b[j] = upd;
        }
        chg[t] = c;   // lane-local; reduced below
    }

    // write belief after 10 iterations
    float* po = belief + off;
    #pragma unroll
    for (int c = 0; c < 4; ++c)
        *(float4*)(po + 4 * c) = make_float4(b[4*c], b[4*c+1], b[4*c+2], b[4*c+3]);

    // full-wave max per t (mixes the wave's 4 rows -- fine, we need a global max)
    #pragma unroll
    for (int t = 0; t < kIters; ++t) {
        float v = chg[t];
        #pragma unroll
        for (int o = 32; o > 0; o >>= 1) v = fmaxf(v, __shfl_xor(v, o));
        chg[t] = v;
    }

    __shared__ float schg[4][kIters];
    if (lane == 0) {
        #pragma unroll
        for (int t = 0; t < kIters; ++t) schg[wave][t] = chg[t];
    }
    __syncthreads();
    if (threadIdx.x < kIters) {
        const int t = threadIdx.x;
        float m = fmaxf(fmaxf(schg[0][t], schg[1][t]),
                        fmaxf(schg[2][t], schg[3][t]));
        atomicMax(&slots[t * kSlots + (blockIdx.x & (kSlots - 1))],
                  __float_as_uint(m));
    }
}

__global__ __launch_bounds__(64) void bu_finalize(
    const unsigned* __restrict__ slots,
    float* __restrict__ iters_out,   // d_out tail, written as float
    int* __restrict__ flag)
{
    const int lane = threadIdx.x & 63;
    float chg[kIters];
    #pragma unroll
    for (int t = 0; t < kIters; ++t) {
        float v = __uint_as_float(slots[t * kSlots + lane]);
        #pragma unroll
        for (int o = 32; o > 0; o >>= 1) v = fmaxf(v, __shfl_xor(v, o));
        chg[t] = v;
    }
    if (threadIdx.x == 0) {
        int iters = 0;
        bool done = false;
        #pragma unroll
        for (int t = 0; t < kIters; ++t) {
            if (!done) iters++;              // iters_next = iters + (done?0:1)
            if (chg[t] < kThresh) done = true;  // done_next = done | (chg < thr)
        }
        *iters_out = (float)iters;
        *flag = (iters < kIters) ? iters : -1;   // -1: b_10 already correct
    }
}

// Rare path: recompute b_k when convergence froze belief before iteration 10.
__global__ __launch_bounds__(256) void bu_phaseC(
    const float* __restrict__ prior,
    const float* __restrict__ lik,
    const float* __restrict__ msg,
    float* __restrict__ belief,
    const int* __restrict__ flag,
    int B)
{
    const int k = *flag;
    if (k < 0) return;
    const int wave = threadIdx.x >> 6;
    const int lane = threadIdx.x & 63;
    const int g    = lane >> 4;
    const int q    = lane & 15;
    const int nUnits = B / 16;   // 16 rows per block-pass
    for (int u = blockIdx.x; u < nUnits; u += gridDim.x) {
        const int row = (u * 4 + wave) * 4 + g;
        const size_t off = (size_t)row * kD + (size_t)q * 16;
        const float* p0 = prior + off;
        const float* p1 = lik   + off;
        const float* p2 = msg   + off;
        const float* p3 = msg   + (size_t)B * kD + off;
        float b[16], W[16];
        #pragma unroll
        for (int c = 0; c < 4; ++c) {
            float4 vb = *(const float4*)(p0 + 4 * c);
            float4 vl = *(const float4*)(p1 + 4 * c);
            float4 v0 = *(const float4*)(p2 + 4 * c);
            float4 v1 = *(const float4*)(p3 + 4 * c);
            b[4*c+0] = vb.x; b[4*c+1] = vb.y; b[4*c+2] = vb.z; b[4*c+3] = vb.w;
            W[4*c+0] = (vl.x + kEps) * (v0.x + kEps) * (v1.x + kEps);
            W[4*c+1] = (vl.y + kEps) * (v0.y + kEps) * (v1.y + kEps);
            W[4*c+2] = (vl.z + kEps) * (v0.z + kEps) * (v1.z + kEps);
            W[4*c+3] = (vl.w + kEps) * (v0.w + kEps) * (v1.w + kEps);
        }
        for (int t = 0; t < k; ++t) {
            float pp[16];
            float s = 0.f;
            #pragma unroll
            for (int j = 0; j < 16; ++j) { pp[j] = (b[j] + kEps) * W[j]; s += pp[j]; }
            s += __shfl_xor(s, 1);
            s += __shfl_xor(s, 2);
            s += __shfl_xor(s, 4);
            s += __shfl_xor(s, 8);
            const float inv = 1.0f / s;
            #pragma unroll
            for (int j = 0; j < 16; ++j) {
                float nb = pp[j] * inv;
                b[j] = b[j] + (nb - b[j]);
            }
        }
        float* po = belief + off;
        #pragma unroll
        for (int c = 0; c < 4; ++c)
            *(float4*)(po + 4 * c) = make_float4(b[4*c], b[4*c+1], b[4*c+2], b[4*c+3]);
    }
}

extern "C" void kernel_launch(void* const* d_in, const int* in_sizes, int n_in,
                              void* d_out, int out_size, void* d_ws, size_t ws_size,
                              hipStream_t stream) {
    const float* prior = (const float*)d_in[0];
    const float* lik   = (const float*)d_in[1];
    const float* msg   = (const float*)d_in[2];
    const int B = in_sizes[0] / kD;          // 131072

    float* belief    = (float*)d_out;
    float* iters_out = belief + (size_t)B * kD;

    int*      flag  = (int*)d_ws;
    unsigned* slots = (unsigned*)((char*)d_ws + 64);

    bu_init<<<1, 256, 0, stream>>>(slots);
    bu_phaseA<<<B / 16, 256, 0, stream>>>(prior, lik, msg, belief, slots, B);
    bu_finalize<<<1, 64, 0, stream>>>(slots, iters_out, flag);
    bu_phaseC<<<512, 256, 0, stream>>>(prior, lik, msg, belief, flag, B);
}

// Round 2
// 136.426 us; speedup vs baseline: 1.0576x; 1.0576x over previous
//
#include <hip/hip_runtime.h>

// BeliefUpdate: b_{t+1} = softmax(log(b_t+eps) + log_lik) = normalize((b_t+eps) * W),
//   W = (lik+eps)*(m0+eps)*(m1+eps).
// Dropping the inner +eps (relative error ~2.6e-8/iter, far below tolerance):
//   b_t = normalize(b_0 * W^t)  -- only serial dep across iterations is u *= W.
// Per-row 10-iter trajectory fully in registers: 8 elems/lane, 32-lane row group.
// Row-sum allreduce: 4x DPP row_ror add (VALU pipe) + 1 ds_swizzle xor16.
// Global per-iter max-change via wave reduce + spread atomicMax; finalize derives
// iters; phaseC recomputes b_k only if converged early (a.s. never here).

typedef float f32x4 __attribute__((ext_vector_type(4)));

static constexpr int   kD      = 256;
static constexpr float kEps    = 1e-10f;
static constexpr float kThresh = 1e-4f;
static constexpr int   kIters  = 10;
static constexpr int   kSlots  = 64;

template<int CTRL>
__device__ __forceinline__ float dpp_add(float v) {
    int t = __builtin_amdgcn_update_dpp(0, __float_as_int(v), CTRL, 0xf, 0xf, true);
    return v + __int_as_float(t);
}
template<int CTRL>
__device__ __forceinline__ float dpp_max(float v) {
    int t = __builtin_amdgcn_update_dpp(0, __float_as_int(v), CTRL, 0xf, 0xf, true);
    return fmaxf(v, __int_as_float(t));
}
__device__ __forceinline__ float swz_xor16(float v) {
    return __int_as_float(__builtin_amdgcn_ds_swizzle(__float_as_int(v), 0x401F));
}

__global__ __launch_bounds__(256) void bu_init(unsigned* __restrict__ slots) {
    for (int i = threadIdx.x; i < kIters * kSlots; i += 256) slots[i] = 0u;
}

// 256 threads = 4 waves; each wave = two 32-lane row groups (8 elems/lane).
__global__ __launch_bounds__(256) void bu_main(
    const float* __restrict__ prior,
    const float* __restrict__ lik,
    const float* __restrict__ msg,
    float* __restrict__ belief,
    unsigned* __restrict__ slots,
    int B)
{
    const int tid  = threadIdx.x;
    const int wave = tid >> 6;
    const int lane = tid & 63;
    const int sub  = lane >> 5;        // which row of the wave's pair
    const int q    = lane & 31;        // position within 32-lane row group
    const int row  = blockIdx.x * 8 + wave * 2 + sub;
    const size_t off = (size_t)row * kD + (size_t)q * 8;

    const f32x4* pb = (const f32x4*)(prior + off);
    const f32x4* pl = (const f32x4*)(lik + off);
    const f32x4* p0 = (const f32x4*)(msg + off);
    const f32x4* p1 = (const f32x4*)(msg + (size_t)B * kD + off);

    f32x4 vb0 = pb[0], vb1 = pb[1];
    f32x4 vl0 = pl[0], vl1 = pl[1];
    f32x4 va0 = p0[0], va1 = p0[1];
    f32x4 vc0 = p1[0], vc1 = p1[1];

    float u[8], W[8], pv[8];
    #pragma unroll
    for (int k = 0; k < 4; ++k) {
        u[k]     = vb0[k];
        u[4 + k] = vb1[k];
        W[k]     = (vl0[k] + kEps) * (va0[k] + kEps) * (vc0[k] + kEps);
        W[4 + k] = (vl1[k] + kEps) * (va1[k] + kEps) * (vc1[k] + kEps);
        pv[k]     = u[k];
        pv[4 + k] = u[4 + k];
    }

    float chg[kIters];
    #pragma unroll
    for (int t = 0; t < kIters; ++t) {
        #pragma unroll
        for (int j = 0; j < 8; ++j) u[j] *= W[j];
        float s = ((u[0] + u[1]) + (u[2] + u[3])) + ((u[4] + u[5]) + (u[6] + u[7]));
        s = dpp_add<0x121>(s);   // row_ror:1
        s = dpp_add<0x122>(s);   // row_ror:2
        s = dpp_add<0x124>(s);   // row_ror:4
        s = dpp_add<0x128>(s);   // row_ror:8  -> full sum within 16-lane row
        s += swz_xor16(s);       // span the 32-lane group
        const float inv = __builtin_amdgcn_rcpf(s);
        float c = 0.f;
        #pragma unroll
        for (int j = 0; j < 8; ++j) {
            float nb = u[j] * inv;
            c = fmaxf(c, fabsf(nb - pv[j]));
            pv[j] = nb;
        }
        chg[t] = c;
    }

    // pv now holds b_10; stream it out without polluting L2/L3 (inputs re-read
    // across timed replays benefit from L3 residency).
    f32x4 o0 = {pv[0], pv[1], pv[2], pv[3]};
    f32x4 o1 = {pv[4], pv[5], pv[6], pv[7]};
    __builtin_nontemporal_store(o0, (f32x4*)(belief + off));
    __builtin_nontemporal_store(o1, (f32x4*)(belief + off) + 1);

    // reduce chg[0..8] across each 32-lane group (chg[9] never affects iters)
    __shared__ float schg[4][2][kIters];
    #pragma unroll
    for (int t = 0; t < kIters - 1; ++t) {
        float v = chg[t];
        v = dpp_max<0x121>(v);
        v = dpp_max<0x122>(v);
        v = dpp_max<0x124>(v);
        v = dpp_max<0x128>(v);
        v = fmaxf(v, swz_xor16(v));
        chg[t] = v;
    }
    if (q == 0) {
        #pragma unroll
        for (int t = 0; t < kIters - 1; ++t) schg[wave][sub][t] = chg[t];
    }
    __syncthreads();
    if (tid < kIters - 1) {
        float m = 0.f;
        #pragma unroll
        for (int w2 = 0; w2 < 4; ++w2) {
            m = fmaxf(m, schg[w2][0][tid]);
            m = fmaxf(m, schg[w2][1][tid]);
        }
        atomicMax(&slots[tid * kSlots + (blockIdx.x & (kSlots - 1))],
                  __float_as_uint(m));
    }
}

__global__ __launch_bounds__(64) void bu_finalize(
    const unsigned* __restrict__ slots,
    float* __restrict__ iters_out,
    int* __restrict__ flag)
{
    const int lane = threadIdx.x & 63;
    float chg[kIters];
    #pragma unroll
    for (int t = 0; t < kIters; ++t) {
        float v = __uint_as_float(slots[t * kSlots + lane]);
        #pragma unroll
        for (int o = 32; o > 0; o >>= 1) v = fmaxf(v, __shfl_xor(v, o));
        chg[t] = v;
    }
    if (threadIdx.x == 0) {
        int iters = 0;
        bool done = false;
        #pragma unroll
        for (int t = 0; t < kIters; ++t) {
            if (!done) iters++;
            if (chg[t] < kThresh) done = true;
        }
        *iters_out = (float)iters;
        *flag = (iters < kIters) ? iters : -1;
    }
}

// Rare path: recompute b_k (eps-exact iteration) when converged before iter 10.
__global__ __launch_bounds__(256) void bu_phaseC(
    const float* __restrict__ prior,
    const float* __restrict__ lik,
    const float* __restrict__ msg,
    float* __restrict__ belief,
    const int* __restrict__ flag,
    int B)
{
    const int k = *flag;
    if (k < 0) return;
    const int wave = threadIdx.x >> 6;
    const int lane = threadIdx.x & 63;
    const int g    = lane >> 4;
    const int q    = lane & 15;
    const int nUnits = B / 16;
    for (int u2 = blockIdx.x; u2 < nUnits; u2 += gridDim.x) {
        const int row = (u2 * 4 + wave) * 4 + g;
        const size_t off = (size_t)row * kD + (size_t)q * 16;
        const float* p0 = prior + off;
        const float* p1 = lik   + off;
        const float* p2 = msg   + off;
        const float* p3 = msg   + (size_t)B * kD + off;
        float b[16], W[16];
        #pragma unroll
        for (int c = 0; c < 4; ++c) {
            float4 vb = *(const float4*)(p0 + 4 * c);
            float4 vl = *(const float4*)(p1 + 4 * c);
            float4 v0 = *(const float4*)(p2 + 4 * c);
            float4 v1 = *(const float4*)(p3 + 4 * c);
            b[4*c+0] = vb.x; b[4*c+1] = vb.y; b[4*c+2] = vb.z; b[4*c+3] = vb.w;
            W[4*c+0] = (vl.x + kEps) * (v0.x + kEps) * (v1.x + kEps);
            W[4*c+1] = (vl.y + kEps) * (v0.y + kEps) * (v1.y + kEps);
            W[4*c+2] = (vl.z + kEps) * (v0.z + kEps) * (v1.z + kEps);
            W[4*c+3] = (vl.w + kEps) * (v0.w + kEps) * (v1.w + kEps);
        }
        for (int t = 0; t < k; ++t) {
            float pp[16];
            float s = 0.f;
            #pragma unroll
            for (int j = 0; j < 16; ++j) { pp[j] = (b[j] + kEps) * W[j]; s += pp[j]; }
            s += __shfl_xor(s, 1);
            s += __shfl_xor(s, 2);
            s += __shfl_xor(s, 4);
            s += __shfl_xor(s, 8);
            const float inv = 1.0f / s;
            #pragma unroll
            for (int j = 0; j < 16; ++j) b[j] = pp[j] * inv;
        }
        float* po = belief + off;
        #pragma unroll
        for (int c = 0; c < 4; ++c)
            *(float4*)(po + 4 * c) = make_float4(b[4*c], b[4*c+1], b[4*c+2], b[4*c+3]);
    }
}

extern "C" void kernel_launch(void* const* d_in, const int* in_sizes, int n_in,
                              void* d_out, int out_size, void* d_ws, size_t ws_size,
                              hipStream_t stream) {
    const float* prior = (const float*)d_in[0];
    const float* lik   = (const float*)d_in[1];
    const float* msg   = (const float*)d_in[2];
    const int B = in_sizes[0] / kD;          // 131072

    float* belief    = (float*)d_out;
    float* iters_out = belief + (size_t)B * kD;

    int*      flag  = (int*)d_ws;
    unsigned* slots = (unsigned*)((char*)d_ws + 64);

    bu_init<<<1, 256, 0, stream>>>(slots);
    bu_main<<<B / 8, 256, 0, stream>>>(prior, lik, msg, belief, slots, B);
    bu_finalize<<<1, 64, 0, stream>>>(slots, iters_out, flag);
    bu_phaseC<<<512, 256, 0, stream>>>(prior, lik, msg, belief, flag, B);
}